// Round 1
// baseline (657.014 us; speedup 1.0000x reference)
//
#include <hip/hip_runtime.h>
#include <stdint.h>

typedef unsigned short ushort_t;
typedef __bf16 bf16x8 __attribute__((ext_vector_type(8)));
typedef float f32x4 __attribute__((ext_vector_type(4)));

// ---- problem constants ----
#define NB   16
#define CIN  256
#define COUT 128
#define HH   128
#define WW   128
#define HP   130
#define WP   130
#define KTAP 9
#define KTOT 2304   // CIN*9

__device__ __forceinline__ ushort_t f2bf(float f) {
  union { float f; uint32_t u; } v; v.f = f;
  uint32_t u = v.u;
  uint32_t r = (u + 0x7fffu + ((u >> 16) & 1u)) >> 16;
  return (ushort_t)r;
}
__device__ __forceinline__ float bf2f(ushort_t b) {
  union { uint32_t u; float f; } v; v.u = ((uint32_t)b) << 16;
  return v.f;
}
__device__ __forceinline__ void gload_lds16(const void* g, void* l) {
  __builtin_amdgcn_global_load_lds((const __attribute__((address_space(1))) void*)g,
                                   (__attribute__((address_space(3))) void*)l, 16, 0, 0);
}

// ---- kernel 1: alpha + sign weights in [tap][o][c] bf16 layout ----
__global__ void prep_w_kernel(const float* __restrict__ w,
                              ushort_t* __restrict__ sgnW,
                              float* __restrict__ alpha) {
  int o = blockIdx.x, t = threadIdx.x;
  float s = 0.f;
  for (int e = t; e < KTOT; e += 256) {
    float v = w[o * KTOT + e];
    s += fabsf(v);
    ushort_t sg = (v > 0.f) ? 0x3F80 : (v < 0.f ? 0xBF80 : 0);
    int c = e / 9;
    int tap = e - c * 9;
    sgnW[(tap * COUT + o) * CIN + c] = sg;
  }
  __shared__ float red[4];
  for (int off = 32; off; off >>= 1) s += __shfl_down(s, off, 64);
  if ((t & 63) == 0) red[t >> 6] = s;
  __syncthreads();
  if (t == 0) alpha[o] = (red[0] + red[1] + red[2] + red[3]) / (float)KTOT;
}

// ---- kernel 2: NCHW f32 -> padded NHWC bf16 transpose ----
__global__ void transpose_kernel(const float* __restrict__ x,
                                 ushort_t* __restrict__ xT) {
  int bid = blockIdx.x;
  int ct = bid & 3;          // 4 c-tiles of 64
  int wt = (bid >> 2) & 1;   // 2 w-tiles of 64
  int h  = (bid >> 3) & 127;
  int b  = bid >> 10;
  int c0 = ct * 64, w0 = wt * 64;
  __shared__ float tile[64][65];
  int t = threadIdx.x;
  int wl = t & 63, cl4 = t >> 6;
  const float* src = x + (((size_t)b * CIN + c0) * HH + h) * WW + w0;
  for (int it = 0; it < 16; ++it) {
    int cl = it * 4 + cl4;
    tile[cl][wl] = src[(size_t)cl * (HH * WW) + wl];
  }
  __syncthreads();
  int cp = t & 31, wi = t >> 5;
  for (int it = 0; it < 8; ++it) {
    int wl2 = it * 8 + wi;
    int cl = cp * 2;
    uint32_t pk = (uint32_t)f2bf(tile[cl][wl2]) |
                  ((uint32_t)f2bf(tile[cl + 1][wl2]) << 16);
    size_t idx = ((((size_t)b * HP + h + 1) * WP) + (w0 + wl2 + 1)) * CIN + c0 + cl;
    *(uint32_t*)(xT + idx) = pk;
  }
}

// ---- kernel 3: implicit-GEMM conv + fused epilogue + pixel-unshuffle ----
__global__ __launch_bounds__(256, 2) void conv_gemm(
    const ushort_t* __restrict__ xT, const ushort_t* __restrict__ sgnW,
    const float* __restrict__ alpha, const float* __restrict__ mv1,
    const float* __restrict__ pw, const float* __restrict__ mv2,
    const float* __restrict__ scale, float* __restrict__ out) {
  __shared__ __align__(16) ushort_t As[128 * 64];
  __shared__ __align__(16) ushort_t Bs[128 * 64];

  int bid = blockIdx.x;
  int wg = ((bid & 7) << 8) | (bid >> 3);   // XCD swizzle (2048 % 8 == 0)
  int b = wg >> 7, h = wg & 127;

  int t = threadIdx.x, wv = t >> 6, l = t & 63;
  int wr = wv >> 1, wc = wv & 1;

  int crow = l >> 3;              // row within 8-row chunk
  int se = (l & 7) ^ crow;        // pre-swizzled source slot (constant)

  f32x4 acc[4][4] = {};

  const ushort_t* xb = xT + ((size_t)b * HP + h) * WP * CIN;

  for (int ks = 0; ks < 36; ++ks) {
    int tap = ks >> 2, i0 = (ks & 3) << 6;
    int kh = (tap >= 6) ? 2 : (tap >= 3 ? 1 : 0);
    int kw = tap - kh * 3;
    __syncthreads();
    const ushort_t* gA = xb + (kh * WP + kw) * CIN + i0 + se * 8;
    const ushort_t* gB = sgnW + tap * (COUT * CIN) + i0 + se * 8;
#pragma unroll
    for (int q = 0; q < 4; ++q) {
      int c = wv * 4 + q;
      int m = c * 8 + crow;
      gload_lds16(gA + (size_t)m * CIN, (char*)As + c * 1024);
      gload_lds16(gB + (size_t)m * CIN, (char*)Bs + c * 1024);
    }
    __syncthreads();
#pragma unroll
    for (int kk = 0; kk < 2; ++kk) {
      bf16x8 av[4], bv[4];
      int lg = l >> 4, rA = l & 15;
#pragma unroll
      for (int mi = 0; mi < 4; ++mi) {
        int m = wr * 64 + mi * 16 + rA;
        int slot = (kk * 4 + lg) ^ (m & 7);
        av[mi] = *(const bf16x8*)((const char*)As + m * 128 + slot * 16);
      }
#pragma unroll
      for (int ni = 0; ni < 4; ++ni) {
        int o = wc * 64 + ni * 16 + rA;
        int slot = (kk * 4 + lg) ^ (o & 7);
        bv[ni] = *(const bf16x8*)((const char*)Bs + o * 128 + slot * 16);
      }
#pragma unroll
      for (int mi = 0; mi < 4; ++mi)
#pragma unroll
        for (int ni = 0; ni < 4; ++ni)
          acc[mi][ni] = __builtin_amdgcn_mfma_f32_16x16x32_bf16(av[mi], bv[ni], acc[mi][ni], 0, 0, 0);
    }
  }

  // fused epilogue: alpha*acc + b1 -> prelu -> +b2 -> +shortcut -> unshuffle store
  float sc0 = scale[0];
  int lg = l >> 4, rA = l & 15;
  const ushort_t* scrow = xT + (((size_t)b * HP + h + 1) * WP + 1) * CIN;
  size_t outBase = (((size_t)b * 512 + (h & 1) * 2) * 64 + (h >> 1)) * 64;
#pragma unroll
  for (int ni = 0; ni < 4; ++ni) {
    int o = wc * 64 + ni * 16 + rA;
    float al = alpha[o], b1 = mv1[o], p = pw[o], b2 = mv2[o];
#pragma unroll
    for (int mi = 0; mi < 4; ++mi) {
#pragma unroll
      for (int r = 0; r < 4; ++r) {
        int w = wr * 64 + mi * 16 + lg * 4 + r;
        float v = acc[mi][ni][r] * al + b1;
        v = v > 0.f ? v : p * v;
        v += b2;
        v += bf2f(scrow[(size_t)w * CIN + o]) * sc0;
        out[outBase + (size_t)(o * 4 + (w & 1)) * 4096 + (w >> 1)] = v;
      }
    }
  }
}

extern "C" void kernel_launch(void* const* d_in, const int* in_sizes, int n_in,
                              void* d_out, int out_size, void* d_ws, size_t ws_size,
                              hipStream_t stream) {
  const float* x      = (const float*)d_in[0];
  const float* conv_w = (const float*)d_in[1];
  const float* mv1    = (const float*)d_in[2];
  const float* pw     = (const float*)d_in[3];
  const float* mv2    = (const float*)d_in[4];
  const float* scale  = (const float*)d_in[5];
  float* out = (float*)d_out;

  const size_t XT_ELEMS = (size_t)NB * HP * WP * CIN;          // 69,222,400
  ushort_t* xT   = (ushort_t*)d_ws;
  ushort_t* sgnW = xT + XT_ELEMS;                               // 9*128*256
  float*    alpha = (float*)(sgnW + (size_t)KTAP * COUT * CIN);

  prep_w_kernel<<<COUT, 256, 0, stream>>>(conv_w, sgnW, alpha);
  hipMemsetAsync(xT, 0, XT_ELEMS * sizeof(ushort_t), stream);
  transpose_kernel<<<NB * HH * 2 * 4, 256, 0, stream>>>(x, xT);
  conv_gemm<<<NB * HH, 256, 0, stream>>>(xT, sgnW, alpha, mv1, pw, mv2, scale, out);
}